// Round 1
// baseline (870.335 us; speedup 1.0000x reference)
//
#include <hip/hip_runtime.h>
#include <hip/hip_bf16.h>
#include <math.h>

// ---------------------------------------------------------------------------
// ContextualAttention: y[b,p,q] = softmax_p( 10 * mm[p] * (Σ_s S[p+s,q+s]) / denom[b,p] ) * mm[p]
//   S[b][u][v] = Σ_c b_in[b,c,u] * f_in[b,c,v]   (K=128 GEMM, bf16x2-split MFMA)
//   s ranges over 9 diagonal shifts dy*64+dx, validity from 2D bounds.
// ---------------------------------------------------------------------------

typedef float f32x4 __attribute__((ext_vector_type(4)));
typedef short bf16x8 __attribute__((ext_vector_type(8)));

#define NB 4
#define NC 128
#define NP 4096ull       // 64*64 spatial positions
#define LOG2E_SCALE 14.426950408889634f   // 10 * log2(e)
#define EPS_TERM (1152.0f * 1e-4f)

// ---- workspace layout (bytes) ----
#define SZ_S      (4ull * NP * NP * 4ull)            // 268435456
#define SZ_BT     (4ull * NP * NC * 2ull)            // 4194304 (bf16 [b][u][c])
#define OFF_S     0ull
#define OFF_BT_HI (OFF_S + SZ_S)
#define OFF_BT_LO (OFF_BT_HI + SZ_BT)
#define OFF_FT_HI (OFF_BT_LO + SZ_BT)
#define OFF_FT_LO (OFF_FT_HI + SZ_BT)
#define OFF_NORM2 (OFF_FT_LO + SZ_BT)                // 4*4096 f32
#define OFF_COEF  (OFF_NORM2 + 4ull * NP * 4ull)     // 4*4096 f32
#define OFF_MM    (OFF_COEF + 4ull * NP * 4ull)      // 4096 f32
#define OFF_PART  (OFF_MM + NP * 4ull)               // 4*16*4096 f32
#define OFF_LINV  (OFF_PART + 4ull * 16ull * NP * 4ull)

// ---------------------------------------------------------------------------
// norm2[b][u] = sum_c b_in[b,c,u]^2
__global__ __launch_bounds__(256) void k_norm2(const float* __restrict__ bin,
                                               float* __restrict__ norm2) {
    int idx = blockIdx.x * 256 + threadIdx.x;       // 16384 = 4*4096
    int b = idx >> 12, u = idx & 4095;
    const float* src = bin + (size_t)b * NC * NP + u;
    float s = 0.f;
#pragma unroll 8
    for (int c = 0; c < NC; ++c) { float x = src[(size_t)c * NP]; s += x * x; }
    norm2[idx] = s;
}

// coef[b][p] = mm[p] * 10*log2(e) / sqrt(boxsum3x3(norm2) + 1152*EPS)
__global__ __launch_bounds__(256) void k_coef(const float* __restrict__ norm2,
                                              const float* __restrict__ mask,
                                              float* __restrict__ coef,
                                              float* __restrict__ mmArr) {
    int idx = blockIdx.x * 256 + threadIdx.x;       // 16384
    int b = idx >> 12, p = idx & 4095;
    int ph = p >> 6, pw = p & 63;
    float ns = 0.f, ms = 0.f;
#pragma unroll
    for (int dy = -1; dy <= 1; ++dy)
#pragma unroll
        for (int dx = -1; dx <= 1; ++dx) {
            int hh = ph + dy, ww = pw + dx;
            if ((unsigned)hh < 64u && (unsigned)ww < 64u) {
                ns += norm2[b * 4096 + hh * 64 + ww];
                // mask_s[h][w] = mask[0,0,8h,8w];  flat: (8h)*512 + 8w
                ms += mask[(size_t)(hh * 512 + ww) * 8];
            }
        }
    float mmv = (ms == 0.f) ? 1.f : 0.f;
    coef[idx] = mmv * LOG2E_SCALE / sqrtf(ns + EPS_TERM);
    if (b == 0) mmArr[p] = mmv;
}

// ---------------------------------------------------------------------------
// Transpose [c][u] f32 -> [u][c] bf16 hi/lo split (per batch, per input array)
__global__ __launch_bounds__(256) void k_convert(const float* __restrict__ fin,
                                                 const float* __restrict__ bin,
                                                 __bf16* __restrict__ bt_hi, __bf16* __restrict__ bt_lo,
                                                 __bf16* __restrict__ ft_hi, __bf16* __restrict__ ft_lo) {
    __shared__ float tile[64][65];
    int u0 = blockIdx.x * 64;
    int k0 = blockIdx.y * 64;
    int z = blockIdx.z;                  // 0..7 : (batch<<1)|arr
    int arr = z & 1, b = z >> 1;
    const float* src = (arr ? fin : bin) + (size_t)b * NC * NP;
    __bf16* dhi = (arr ? ft_hi : bt_hi) + (size_t)b * NP * NC;
    __bf16* dlo = (arr ? ft_lo : bt_lo) + (size_t)b * NP * NC;
    int t = threadIdx.x;
#pragma unroll
    for (int i = 0; i < 16; ++i) {
        int lin = i * 256 + t;
        int kl = lin >> 6, ul = lin & 63;
        tile[kl][ul] = src[(size_t)(k0 + kl) * NP + u0 + ul];
    }
    __syncthreads();
#pragma unroll
    for (int i = 0; i < 16; ++i) {
        int lin = i * 256 + t;
        int ul = lin >> 6, kl = lin & 63;   // consecutive t -> consecutive kl (coalesced out)
        float x = tile[kl][ul];
        __bf16 h = (__bf16)x;
        float hf = (float)h;
        __bf16 l = (__bf16)(x - hf);
        size_t o = (size_t)(u0 + ul) * NC + (k0 + kl);
        dhi[o] = h; dlo[o] = l;
    }
}

// ---------------------------------------------------------------------------
// S[b][u][v] = sum_c bT[u][c] * fT[v][c]  via 16x16x32 bf16 MFMA, 3-term split.
// Block: 256 thr = 4 waves (2x2), tile 128x128; each wave 64x64 (4x4 MFMA tiles).
__global__ __launch_bounds__(256) void k_matmul(const __bf16* __restrict__ bt_hi,
                                                const __bf16* __restrict__ bt_lo,
                                                const __bf16* __restrict__ ft_hi,
                                                const __bf16* __restrict__ ft_lo,
                                                float* __restrict__ S) {
    int t = threadIdx.x;
    int lane = t & 63;
    int w = t >> 6;
    int b = blockIdx.z;
    int m_base = blockIdx.y * 128 + (w >> 1) * 64;
    int n_base = blockIdx.x * 128 + (w & 1) * 64;
    int l15 = lane & 15;
    int quad = lane >> 4;
    size_t bo = (size_t)b * NP * NC;
    const __bf16* Ah = bt_hi + bo;
    const __bf16* Al = bt_lo + bo;
    const __bf16* Bh = ft_hi + bo;
    const __bf16* Bl = ft_lo + bo;

    f32x4 acc[4][4];
#pragma unroll
    for (int i = 0; i < 4; ++i)
#pragma unroll
        for (int j = 0; j < 4; ++j) acc[i][j] = (f32x4){0.f, 0.f, 0.f, 0.f};

#pragma unroll
    for (int ks = 0; ks < 4; ++ks) {
        int k = ks * 32 + quad * 8;      // A[m=l15][k..k+7], contiguous in memory
        bf16x8 ah[4], al[4], bh[4], bl[4];
#pragma unroll
        for (int mt = 0; mt < 4; ++mt) {
            size_t o = (size_t)(m_base + mt * 16 + l15) * NC + k;
            ah[mt] = *(const bf16x8*)(Ah + o);
            al[mt] = *(const bf16x8*)(Al + o);
        }
#pragma unroll
        for (int nt = 0; nt < 4; ++nt) {
            size_t o = (size_t)(n_base + nt * 16 + l15) * NC + k;
            bh[nt] = *(const bf16x8*)(Bh + o);
            bl[nt] = *(const bf16x8*)(Bl + o);
        }
#pragma unroll
        for (int mt = 0; mt < 4; ++mt)
#pragma unroll
            for (int nt = 0; nt < 4; ++nt) {
                acc[mt][nt] = __builtin_amdgcn_mfma_f32_16x16x32_bf16(ah[mt], bh[nt], acc[mt][nt], 0, 0, 0);
                acc[mt][nt] = __builtin_amdgcn_mfma_f32_16x16x32_bf16(ah[mt], bl[nt], acc[mt][nt], 0, 0, 0);
                acc[mt][nt] = __builtin_amdgcn_mfma_f32_16x16x32_bf16(al[mt], bh[nt], acc[mt][nt], 0, 0, 0);
            }
    }
    // C/D layout (m89-verified): col = lane&15, row = quad*4 + reg
    float* Sb = S + (size_t)b * NP * NP;
#pragma unroll
    for (int mt = 0; mt < 4; ++mt)
#pragma unroll
        for (int nt = 0; nt < 4; ++nt) {
            int col = n_base + nt * 16 + l15;
            int row0 = m_base + mt * 16 + quad * 4;
#pragma unroll
            for (int r = 0; r < 4; ++r)
                Sb[(size_t)(row0 + r) * NP + col] = acc[mt][nt][r];
        }
}

// ---------------------------------------------------------------------------
// Pass A: e = exp2(coef[p] * Σ_s S[p+s,q+s]); out <- e; partial row-sums per (b,pchunk,q)
__global__ __launch_bounds__(256) void k_scores(const float* __restrict__ S,
                                                const float* __restrict__ coef,
                                                float* __restrict__ out,
                                                float* __restrict__ part) {
    int t = threadIdx.x;
    int b = blockIdx.z;
    int pc = blockIdx.y;
    int q = blockIdx.x * 256 + t;
    int qh = q >> 6, qw = q & 63;
    const float* Sb = S + (size_t)b * NP * NP;
    float* outb = out + (size_t)b * NP * NP;
    const float* cf = coef + b * 4096;
    float acc = 0.f;
    for (int pi = 0; pi < 256; ++pi) {
        int p = pc * 256 + pi;
        int ph = p >> 6, pw = p & 63;
        const float* Sp = Sb + (size_t)p * NP + q;
        float y = 0.f;
#pragma unroll
        for (int dy = -1; dy <= 1; ++dy) {
            bool okh = ((unsigned)(ph + dy) < 64u) & ((unsigned)(qh + dy) < 64u);
#pragma unroll
            for (int dx = -1; dx <= 1; ++dx) {
                bool ok = okh & ((unsigned)(pw + dx) < 64u) & ((unsigned)(qw + dx) < 64u);
                int s = dy * 64 + dx;
                float v = ok ? Sp[(ptrdiff_t)s * 4097] : 0.f;   // (p+s)*4096 + (q+s)
                y += v;
            }
        }
        float e = exp2f(cf[p] * y);     // masked p: cf=0 -> e=1, matches softmax(0)
        outb[(size_t)p * NP + q] = e;
        acc += e;
    }
    part[(size_t)(b * 16 + pc) * NP + q] = acc;
}

// linv[b][q] = 1 / Σ_pc part
__global__ __launch_bounds__(256) void k_rsum(const float* __restrict__ part,
                                              float* __restrict__ linv) {
    int idx = blockIdx.x * 256 + threadIdx.x;  // 16384
    int b = idx >> 12, q = idx & 4095;
    float s = 0.f;
#pragma unroll
    for (int pc = 0; pc < 16; ++pc) s += part[(size_t)(b * 16 + pc) * NP + q];
    linv[idx] = 1.0f / s;
}

// out[b][p][q] *= mm[p] * linv[b][q]
__global__ __launch_bounds__(256) void k_fixup(float* __restrict__ out,
                                               const float* __restrict__ mmArr,
                                               const float* __restrict__ linv) {
    int bp = blockIdx.x;                       // 16384 rows
    int b = bp >> 12, p = bp & 4095;
    float mv = mmArr[p];
    float* row = out + (size_t)bp * NP;
    const float* lv = linv + b * 4096;
    int t = threadIdx.x;
#pragma unroll
    for (int it = 0; it < 4; ++it) {
        int q = it * 1024 + t * 4;
        f32x4 v = *(f32x4*)(row + q);
        f32x4 L = *(const f32x4*)(lv + q);
        v.x *= mv * L.x; v.y *= mv * L.y; v.z *= mv * L.z; v.w *= mv * L.w;
        *(f32x4*)(row + q) = v;
    }
}

// ---------------------------------------------------------------------------
extern "C" void kernel_launch(void* const* d_in, const int* in_sizes, int n_in,
                              void* d_out, int out_size, void* d_ws, size_t ws_size,
                              hipStream_t stream) {
    (void)in_sizes; (void)n_in; (void)out_size; (void)ws_size;
    const float* f_in = (const float*)d_in[0];
    const float* b_in = (const float*)d_in[1];
    const float* mask = (const float*)d_in[2];
    float* out = (float*)d_out;
    char* ws = (char*)d_ws;

    float*  S     = (float*)(ws + OFF_S);
    __bf16* bt_hi = (__bf16*)(ws + OFF_BT_HI);
    __bf16* bt_lo = (__bf16*)(ws + OFF_BT_LO);
    __bf16* ft_hi = (__bf16*)(ws + OFF_FT_HI);
    __bf16* ft_lo = (__bf16*)(ws + OFF_FT_LO);
    float*  norm2 = (float*)(ws + OFF_NORM2);
    float*  coef  = (float*)(ws + OFF_COEF);
    float*  mmArr = (float*)(ws + OFF_MM);
    float*  part  = (float*)(ws + OFF_PART);
    float*  linv  = (float*)(ws + OFF_LINV);

    k_norm2  <<<64, 256, 0, stream>>>(b_in, norm2);
    k_coef   <<<64, 256, 0, stream>>>(norm2, mask, coef, mmArr);
    k_convert<<<dim3(64, 2, 8), 256, 0, stream>>>(f_in, b_in, bt_hi, bt_lo, ft_hi, ft_lo);
    k_matmul <<<dim3(32, 32, 4), 256, 0, stream>>>(bt_hi, bt_lo, ft_hi, ft_lo, S);
    k_scores <<<dim3(16, 16, 4), 256, 0, stream>>>(S, coef, out, part);
    k_rsum   <<<64, 256, 0, stream>>>(part, linv);
    k_fixup  <<<16384, 256, 0, stream>>>(out, mmArr, linv);
}

// Round 2
// 758.758 us; speedup vs baseline: 1.1471x; 1.1471x over previous
//
#include <hip/hip_runtime.h>
#include <hip/hip_bf16.h>
#include <math.h>

// ---------------------------------------------------------------------------
// ContextualAttention: y[b,p,q] = softmax_p( 10 * mm[p] * (Σ_s S[p+s,q+s]) / denom[b,p] ) * mm[p]
//   S[b][u][v] = Σ_c b_in[b,c,u] * f_in[b,c,v]   (K=128 GEMM, bf16x2-split MFMA)
//   s = dy*64+dx over 9 diagonal flat shifts; validity from 2D bounds.
// Pass A computes column sums of e=exp2(coef*T) (no store); pass B recomputes
// e and writes e*mm[p]*linv[b][q].
// ---------------------------------------------------------------------------

typedef float f32x4 __attribute__((ext_vector_type(4)));
typedef short bf16x8 __attribute__((ext_vector_type(8)));

#define NB 4
#define NC 128
#define NP 4096ull       // 64*64 spatial positions
#define LOG2E_SCALE 14.426950408889634f   // 10 * log2(e)
#define EPS_TERM (1152.0f * 1e-4f)

// ---- workspace layout (bytes) ----
// 1 KB guard bands before/after S: stencil edge elements read up to 4 B below
// and 256 B above S (they are zeroed after load, but must not fault).
#define SZ_S      (4ull * NP * NP * 4ull)            // 268435456
#define SZ_BT     (4ull * NP * NC * 2ull)            // 4194304 (bf16 [b][u][c])
#define OFF_S     1024ull
#define OFF_BT_HI (OFF_S + SZ_S + 1024ull)
#define OFF_BT_LO (OFF_BT_HI + SZ_BT)
#define OFF_FT_HI (OFF_BT_LO + SZ_BT)
#define OFF_FT_LO (OFF_FT_HI + SZ_BT)
#define OFF_NORM2 (OFF_FT_LO + SZ_BT)                // 4*4096 f32
#define OFF_COEF  (OFF_NORM2 + 4ull * NP * 4ull)     // 4*4096 f32
#define OFF_MM    (OFF_COEF + 4ull * NP * 4ull)      // 4096 f32
#define OFF_PART  (OFF_MM + NP * 4ull)               // 4*128*4096 f32 = 8 MB
#define OFF_LINV  (OFF_PART + 4ull * 128ull * NP * 4ull)

// ---------------------------------------------------------------------------
// norm2[b][u] = sum_c b_in[b,c,u]^2
__global__ __launch_bounds__(256) void k_norm2(const float* __restrict__ bin,
                                               float* __restrict__ norm2) {
    int idx = blockIdx.x * 256 + threadIdx.x;       // 16384 = 4*4096
    int b = idx >> 12, u = idx & 4095;
    const float* src = bin + (size_t)b * NC * NP + u;
    float s = 0.f;
#pragma unroll 8
    for (int c = 0; c < NC; ++c) { float x = src[(size_t)c * NP]; s += x * x; }
    norm2[idx] = s;
}

// coef[b][p] = mm[p] * 10*log2(e) / sqrt(boxsum3x3(norm2) + 1152*EPS)
__global__ __launch_bounds__(256) void k_coef(const float* __restrict__ norm2,
                                              const float* __restrict__ mask,
                                              float* __restrict__ coef,
                                              float* __restrict__ mmArr) {
    int idx = blockIdx.x * 256 + threadIdx.x;       // 16384
    int b = idx >> 12, p = idx & 4095;
    int ph = p >> 6, pw = p & 63;
    float ns = 0.f, ms = 0.f;
#pragma unroll
    for (int dy = -1; dy <= 1; ++dy)
#pragma unroll
        for (int dx = -1; dx <= 1; ++dx) {
            int hh = ph + dy, ww = pw + dx;
            if ((unsigned)hh < 64u && (unsigned)ww < 64u) {
                ns += norm2[b * 4096 + hh * 64 + ww];
                ms += mask[(size_t)(hh * 512 + ww) * 8];
            }
        }
    float mmv = (ms == 0.f) ? 1.f : 0.f;
    coef[idx] = mmv * LOG2E_SCALE / sqrtf(ns + EPS_TERM);
    if (b == 0) mmArr[p] = mmv;
}

// ---------------------------------------------------------------------------
// Transpose [c][u] f32 -> [u][c] bf16 hi/lo split (per batch, per input array)
__global__ __launch_bounds__(256) void k_convert(const float* __restrict__ fin,
                                                 const float* __restrict__ bin,
                                                 __bf16* __restrict__ bt_hi, __bf16* __restrict__ bt_lo,
                                                 __bf16* __restrict__ ft_hi, __bf16* __restrict__ ft_lo) {
    __shared__ float tile[64][65];
    int u0 = blockIdx.x * 64;
    int k0 = blockIdx.y * 64;
    int z = blockIdx.z;                  // 0..7 : (batch<<1)|arr
    int arr = z & 1, b = z >> 1;
    const float* src = (arr ? fin : bin) + (size_t)b * NC * NP;
    __bf16* dhi = (arr ? ft_hi : bt_hi) + (size_t)b * NP * NC;
    __bf16* dlo = (arr ? ft_lo : bt_lo) + (size_t)b * NP * NC;
    int t = threadIdx.x;
#pragma unroll
    for (int i = 0; i < 16; ++i) {
        int lin = i * 256 + t;
        int kl = lin >> 6, ul = lin & 63;
        tile[kl][ul] = src[(size_t)(k0 + kl) * NP + u0 + ul];
    }
    __syncthreads();
#pragma unroll
    for (int i = 0; i < 16; ++i) {
        int lin = i * 256 + t;
        int ul = lin >> 6, kl = lin & 63;   // consecutive t -> consecutive kl (coalesced out)
        float x = tile[kl][ul];
        __bf16 h = (__bf16)x;
        float hf = (float)h;
        __bf16 l = (__bf16)(x - hf);
        size_t o = (size_t)(u0 + ul) * NC + (k0 + kl);
        dhi[o] = h; dlo[o] = l;
    }
}

// ---------------------------------------------------------------------------
// S[b][u][v] = sum_c bT[u][c] * fT[v][c]  via 16x16x32 bf16 MFMA, 3-term split.
// Block: 256 thr = 4 waves (2x2), tile 128x128; each wave 64x64 (4x4 MFMA tiles).
__global__ __launch_bounds__(256) void k_matmul(const __bf16* __restrict__ bt_hi,
                                                const __bf16* __restrict__ bt_lo,
                                                const __bf16* __restrict__ ft_hi,
                                                const __bf16* __restrict__ ft_lo,
                                                float* __restrict__ S) {
    int t = threadIdx.x;
    int lane = t & 63;
    int w = t >> 6;
    int b = blockIdx.z;
    int m_base = blockIdx.y * 128 + (w >> 1) * 64;
    int n_base = blockIdx.x * 128 + (w & 1) * 64;
    int l15 = lane & 15;
    int quad = lane >> 4;
    size_t bo = (size_t)b * NP * NC;
    const __bf16* Ah = bt_hi + bo;
    const __bf16* Al = bt_lo + bo;
    const __bf16* Bh = ft_hi + bo;
    const __bf16* Bl = ft_lo + bo;

    f32x4 acc[4][4];
#pragma unroll
    for (int i = 0; i < 4; ++i)
#pragma unroll
        for (int j = 0; j < 4; ++j) acc[i][j] = (f32x4){0.f, 0.f, 0.f, 0.f};

#pragma unroll
    for (int ks = 0; ks < 4; ++ks) {
        int k = ks * 32 + quad * 8;      // A[m=l15][k..k+7], contiguous in memory
        bf16x8 ah[4], al[4], bh[4], bl[4];
#pragma unroll
        for (int mt = 0; mt < 4; ++mt) {
            size_t o = (size_t)(m_base + mt * 16 + l15) * NC + k;
            ah[mt] = *(const bf16x8*)(Ah + o);
            al[mt] = *(const bf16x8*)(Al + o);
        }
#pragma unroll
        for (int nt = 0; nt < 4; ++nt) {
            size_t o = (size_t)(n_base + nt * 16 + l15) * NC + k;
            bh[nt] = *(const bf16x8*)(Bh + o);
            bl[nt] = *(const bf16x8*)(Bl + o);
        }
#pragma unroll
        for (int mt = 0; mt < 4; ++mt)
#pragma unroll
            for (int nt = 0; nt < 4; ++nt) {
                acc[mt][nt] = __builtin_amdgcn_mfma_f32_16x16x32_bf16(ah[mt], bh[nt], acc[mt][nt], 0, 0, 0);
                acc[mt][nt] = __builtin_amdgcn_mfma_f32_16x16x32_bf16(ah[mt], bl[nt], acc[mt][nt], 0, 0, 0);
                acc[mt][nt] = __builtin_amdgcn_mfma_f32_16x16x32_bf16(al[mt], bh[nt], acc[mt][nt], 0, 0, 0);
            }
    }
    // C/D layout (m89-verified): col = lane&15, row = quad*4 + reg
    float* Sb = S + (size_t)b * NP * NP;
#pragma unroll
    for (int mt = 0; mt < 4; ++mt)
#pragma unroll
        for (int nt = 0; nt < 4; ++nt) {
            int col = n_base + nt * 16 + l15;
            int row0 = m_base + mt * 16 + quad * 4;
#pragma unroll
            for (int r = 0; r < 4; ++r)
                Sb[(size_t)(row0 + r) * NP + col] = acc[mt][nt][r];
        }
}

// ---------------------------------------------------------------------------
// 9-tap diagonal stencil over S, 4 q per thread. Branch-free: loads always
// issue (safe offset 0 when tap invalid), results zeroed by cndmask.
__device__ __forceinline__ f32x4 stencil9(const float* __restrict__ rowbase,
                                          int ph, int pw, int qh, int qw0) {
    f32x4 y = {0.f, 0.f, 0.f, 0.f};
#pragma unroll
    for (int dy = -1; dy <= 1; ++dy) {
        bool okh = ((unsigned)(ph + dy) < 64u) & ((unsigned)(qh + dy) < 64u);
#pragma unroll
        for (int dx = -1; dx <= 1; ++dx) {
            bool ok = okh & ((unsigned)(pw + dx) < 64u);
            const int s = dy * 64 + dx;
            ptrdiff_t off = ok ? (ptrdiff_t)s * 4097 : 0;
            f32x4 t = *(const f32x4*)(rowbase + off);
            if (!ok) t = (f32x4){0.f, 0.f, 0.f, 0.f};
            if (dx == -1 && qw0 == 0)  t.x = 0.f;   // qw=0  has no left tap
            if (dx == 1  && qw0 == 60) t.w = 0.f;   // qw=63 has no right tap
            y += t;
        }
    }
    return y;
}

// Pass A: acc[q] += exp2(coef[p] * T[p][q]) over a 32-p chunk; write partials.
__global__ __launch_bounds__(256) void k_sumexp(const float* __restrict__ S,
                                                const float* __restrict__ coef,
                                                float* __restrict__ part) {
    int t = threadIdx.x;
    int b = blockIdx.z;
    int pc = blockIdx.y;                       // 0..127
    int q0 = blockIdx.x * 1024 + t * 4;
    int qh = q0 >> 6, qw0 = q0 & 63;
    const float* Sb = S + (size_t)b * NP * NP;
    const float* cf = coef + (b << 12);
    f32x4 acc = {0.f, 0.f, 0.f, 0.f};
    for (int pi = 0; pi < 32; ++pi) {
        int p = pc * 32 + pi;
        int ph = p >> 6, pw = p & 63;
        const float* rowbase = Sb + (size_t)p * NP + q0;
        f32x4 y = stencil9(rowbase, ph, pw, qh, qw0);
        float c = cf[p];
        acc.x += exp2f(c * y.x);
        acc.y += exp2f(c * y.y);
        acc.z += exp2f(c * y.z);
        acc.w += exp2f(c * y.w);
    }
    *(f32x4*)(part + ((size_t)(b * 128 + pc) << 12) + q0) = acc;
}

// linv[b][q] = 1 / Σ_pc part
__global__ __launch_bounds__(256) void k_rsum(const float* __restrict__ part,
                                              float* __restrict__ linv) {
    int idx = blockIdx.x * 256 + threadIdx.x;  // 16384
    int b = idx >> 12, q = idx & 4095;
    float s = 0.f;
    for (int pc = 0; pc < 128; ++pc) s += part[((size_t)(b * 128 + pc) << 12) + q];
    linv[idx] = 1.0f / s;
}

// Pass B: out[b][p][q] = exp2(coef[p]*T[p][q]) * mm[p] * linv[b][q]
__global__ __launch_bounds__(256) void k_write(const float* __restrict__ S,
                                               const float* __restrict__ coef,
                                               const float* __restrict__ mmArr,
                                               const float* __restrict__ linv,
                                               float* __restrict__ out) {
    int t = threadIdx.x;
    int b = blockIdx.z;
    int pc = blockIdx.y;                       // 0..127
    int q0 = blockIdx.x * 1024 + t * 4;
    int qh = q0 >> 6, qw0 = q0 & 63;
    const float* Sb = S + (size_t)b * NP * NP;
    float* outb = out + (size_t)b * NP * NP;
    const float* cf = coef + (b << 12);
    f32x4 L = *(const f32x4*)(linv + (b << 12) + q0);
    for (int pi = 0; pi < 32; ++pi) {
        int p = pc * 32 + pi;
        int ph = p >> 6, pw = p & 63;
        const float* rowbase = Sb + (size_t)p * NP + q0;
        f32x4 y = stencil9(rowbase, ph, pw, qh, qw0);
        float c = cf[p];
        float mv = mmArr[p];
        f32x4 o;
        o.x = exp2f(c * y.x) * mv * L.x;
        o.y = exp2f(c * y.y) * mv * L.y;
        o.z = exp2f(c * y.z) * mv * L.z;
        o.w = exp2f(c * y.w) * mv * L.w;
        *(f32x4*)(outb + (size_t)p * NP + q0) = o;
    }
}

// ---------------------------------------------------------------------------
extern "C" void kernel_launch(void* const* d_in, const int* in_sizes, int n_in,
                              void* d_out, int out_size, void* d_ws, size_t ws_size,
                              hipStream_t stream) {
    (void)in_sizes; (void)n_in; (void)out_size; (void)ws_size;
    const float* f_in = (const float*)d_in[0];
    const float* b_in = (const float*)d_in[1];
    const float* mask = (const float*)d_in[2];
    float* out = (float*)d_out;
    char* ws = (char*)d_ws;

    float*  S     = (float*)(ws + OFF_S);
    __bf16* bt_hi = (__bf16*)(ws + OFF_BT_HI);
    __bf16* bt_lo = (__bf16*)(ws + OFF_BT_LO);
    __bf16* ft_hi = (__bf16*)(ws + OFF_FT_HI);
    __bf16* ft_lo = (__bf16*)(ws + OFF_FT_LO);
    float*  norm2 = (float*)(ws + OFF_NORM2);
    float*  coef  = (float*)(ws + OFF_COEF);
    float*  mmArr = (float*)(ws + OFF_MM);
    float*  part  = (float*)(ws + OFF_PART);
    float*  linv  = (float*)(ws + OFF_LINV);

    k_norm2  <<<64, 256, 0, stream>>>(b_in, norm2);
    k_coef   <<<64, 256, 0, stream>>>(norm2, mask, coef, mmArr);
    k_convert<<<dim3(64, 2, 8), 256, 0, stream>>>(f_in, b_in, bt_hi, bt_lo, ft_hi, ft_lo);
    k_matmul <<<dim3(32, 32, 4), 256, 0, stream>>>(bt_hi, bt_lo, ft_hi, ft_lo, S);
    k_sumexp <<<dim3(4, 128, 4), 256, 0, stream>>>(S, coef, part);
    k_rsum   <<<64, 256, 0, stream>>>(part, linv);
    k_write  <<<dim3(4, 128, 4), 256, 0, stream>>>(S, coef, mmArr, linv, out);
}